// Round 4
// baseline (254.534 us; speedup 1.0000x reference)
//
#include <hip/hip_runtime.h>

// ---------------- problem constants ----------------
#define NTOK   32768
#define DIM    512            // bytes per fp8 row too
#define NCODE  4096
#define NELEM  (NTOK*DIM)     // 16777216
#define COMMIT 0.25
#define ESCALE 8192.0f        // 2^13: lifts emb (~2.4e-4) into e4m3 normal range
#define EINV   (1.0f/4096.0f) // 2^-12: score = en - 2*(acc/8192) = en - acc*2^-12
#define KSCL   262144.0f      // 2^18 key quantizer
#define KOFF   65536.0f       // 0.25 * 2^18 (covers |s| <= 0.25 hard bound)
// EINV*KSCL = 64: key = fmaf(en,KSCL,KOFF) - 64*acc (same ordering, fewer ops)

// ---------------- ws layout (bytes) ----------------
#define OFF_Z8      0ULL              // fp8 z: 16777216
#define OFF_E8      16777216ULL       // fp8 e*8192: 2097152
#define OFF_EN32    18874368ULL       // float[4096] = 16384
#define OFF_ROWMIN  18890752ULL       // u32[32768] = 131072 (packed key20|code12)
#define OFF_COUNTS  19021824ULL       // u32[4096] = 16384
#define OFF_SSE     19038208ULL       // double[256] = 2048

typedef int   v8i  __attribute__((ext_vector_type(8)));
typedef float v16f __attribute__((ext_vector_type(16)));

#define GLOBAL_AS __attribute__((address_space(1)))
#define LDS_AS    __attribute__((address_space(3)))

__device__ __forceinline__ void gld16(const void* g, void* l) {
    // async global->LDS, 16B/lane; LDS dest = wave-uniform base + lane*16
    __builtin_amdgcn_global_load_lds((const GLOBAL_AS unsigned int*)g,
                                     (LDS_AS unsigned int*)l, 16, 0, 0);
}

// ---------------- 1. fp32 -> fp8 e4m3 conversion (+ counts/sse init) ----------
__global__ void conv_kernel(const float* __restrict__ z, const float* __restrict__ e,
                            unsigned* __restrict__ z8, unsigned* __restrict__ e8,
                            unsigned* __restrict__ counts, double* __restrict__ sse) {
    const int ZI = NELEM / 16;                 // 1048576 (16 floats -> 16 fp8 per thread)
    const int TI = ZI + (NCODE * DIM) / 16;    // +131072
    int i = blockIdx.x * blockDim.x + threadIdx.x;
    if (i < NCODE) counts[i] = 0u;
    if (i < 256)   sse[i] = 0.0;
    if (i >= TI) return;
    const float4* src; unsigned* dst; int j; float sc;
    if (i < ZI) { src = (const float4*)z; dst = z8; j = i; sc = 1.0f; }
    else        { src = (const float4*)e; dst = e8; j = i - ZI; sc = ESCALE; }
    uint4 o;
#pragma unroll
    for (int q = 0; q < 4; q++) {
        float4 v = src[j * 4 + q];
        int r = 0;
        r = __builtin_amdgcn_cvt_pk_fp8_f32(v.x * sc, v.y * sc, r, false);
        r = __builtin_amdgcn_cvt_pk_fp8_f32(v.z * sc, v.w * sc, r, true);
        (&o.x)[q] = (unsigned)r;
    }
    ((uint4*)dst)[j] = o;
}

// ---------------- 2. ||e_k||^2 (exact f32 via f64 accumulate) ----------------
__global__ void enorm_kernel(const float* __restrict__ emb, float* __restrict__ en32) {
    int gw = (blockIdx.x * blockDim.x + threadIdx.x) >> 6;   // wave id = code
    int lane = threadIdx.x & 63;
    if (gw >= NCODE) return;
    const float4* p = (const float4*)(emb + (size_t)gw * DIM);
    float4 a = p[lane * 2], b = p[lane * 2 + 1];
    double s = (double)a.x*a.x + (double)a.y*a.y + (double)a.z*a.z + (double)a.w*a.w
             + (double)b.x*b.x + (double)b.y*b.y + (double)b.z*b.z + (double)b.w*b.w;
    for (int off = 32; off; off >>= 1) s += __shfl_down(s, off);
    if (lane == 0) en32[gw] = (float)s;
}

// ---------------- 3. persistent-code-loop MX-fp8 score pass (v3) -----------
// M-rep=2 restructure: each wave owns 64 token rows x 32 codes (za[2][8] A in
// 128 VGPRs, 4 MFMA chains). Block of 4 waves = (t: tile-of-pair, wn: code
// half) consumes TWO 64-code tiles per iteration -> every B fragment is read
// by exactly ONE wave (was 2): LDS ds_read demand/CU-iter 1536 -> 768 cy,
// below the 1101-cy MFMA pipe floor.
//   - e staged in PAIRS (64KB), double-buffered: 128KB + en 16KB = 144KB LDS
//     -> 1 block/CU, 4 waves pinned one-per-SIMD. Grid 512 = 2 clean rounds.
//   - counted vmcnt: 16 gld16/pair/wave; entry waits vmcnt(16) (16 newest =
//     pair ct+1); vmcnt(0) only on peeled last iter.
//   - score folded to 5 VALU/output via key = fmaf(sum,-64,pre),
//     pre = fmaf(en,KSCL,KOFF); score deferred after ct+2 stage issue.
// Swizzle: granule g of row r at slot g^(r&31); pair-row rr has rr&31 ==
// tile-row&31 (tiles are 64 rows), so read addressing is unchanged.
__global__ __launch_bounds__(256, 1)
void score_pass(const unsigned char* __restrict__ z8, const unsigned char* __restrict__ e8,
                const float* __restrict__ en32,
                unsigned* __restrict__ rowmin) {
    __shared__ __align__(16) unsigned char sE[4 * 32768];   // 2 pairs x 2 tiles
    __shared__ __align__(16) float sEn[NCODE];               // 16KB code norms
    const int tid = threadIdx.x;
    const int row0 = blockIdx.x * 64;    // token rows of this block
    const int wv = tid >> 6, ln = tid & 63;
    const int t  = wv & 1;               // which tile of the pair
    const int wn = wv >> 1;              // code half within the tile
    const int c = ln & 31, h = ln >> 5;

    // ---- stage z tile (32KB) into buf2 region: gld16 #q covers rows {2q,2q+1}
#pragma unroll
    for (int s = 0; s < 8; s++) {
        int q = wv * 8 + s;
        int r = 2 * q + h;
        unsigned g = (unsigned)(c ^ (r & 31));
        gld16(z8 + (size_t)(row0 + r) * 512 + g * 16u, sE + 65536 + q * 1024);
    }
    // ---- stage en32 -> sEn: 16 x 1KB chunks, 4 per wave
#pragma unroll
    for (int s = 0; s < 4; s++) {
        int chunk = wv * 4 + s;
        gld16((const unsigned char*)en32 + chunk * 1024 + (unsigned)(ln * 16),
              (unsigned char*)sEn + chunk * 1024);
    }

    // per-lane pair-stage source offsets (ct-invariant): 16 x 1KB chunks/wave
    unsigned eoff[16];
#pragma unroll
    for (int s = 0; s < 16; s++) {
        int q = wv * 16 + s;             // chunk 0..63 of the 64KB pair
        int rr = 2 * q + h;              // code-row 0..127 within pair
        unsigned g = (unsigned)(c ^ (rr & 31));
        eoff[s] = (unsigned)(rr * 512) + g * 16u;
    }

    // pin issue order: z+en (12) strictly BEFORE pair0 (16), so vmcnt(16)
    // below provably means "z and en staged".
    __builtin_amdgcn_sched_barrier(0);

    // ---- stage e-pair 0 into buf[0,1]
#pragma unroll
    for (int s = 0; s < 16; s++)
        gld16(e8 + eoff[s], sE + (wv * 16 + s) * 1024);

    asm volatile("s_waitcnt vmcnt(16)" ::: "memory");   // z + en resident
    __builtin_amdgcn_s_barrier();

    // ---- hoist A fragments: 64 z rows x K=512 -> za[2][8] (128 VGPRs)
    const int nrow = (wn * 32 + c) * 512;
    v8i za[2][8];
#pragma unroll
    for (int m = 0; m < 2; m++) {
        const int mbase = 65536 + (m * 32 + c) * 512;
#pragma unroll
        for (int kt = 0; kt < 8; kt++) {
            int G = kt * 4 + 2 * h;
            union { uint4 u[2]; v8i v; } av;
            av.u[0] = *(const uint4*)(sE + mbase + (((G    ) ^ c) * 16));
            av.u[1] = *(const uint4*)(sE + mbase + (((G + 1) ^ c) * 16));
            za[m][kt] = av.v;
        }
    }
    asm volatile("s_waitcnt lgkmcnt(0)" ::: "memory");
    __builtin_amdgcn_s_barrier();        // all waves done with z region

    // ---- stage e-pair 1 into buf[2,3]
#pragma unroll
    for (int s = 0; s < 16; s++)
        gld16(e8 + 65536 + eoff[s], sE + 65536 + (wv * 16 + s) * 1024);

    unsigned runmin[2][16];
#pragma unroll
    for (int m = 0; m < 2; m++)
#pragma unroll
    for (int reg = 0; reg < 16; reg++) runmin[m][reg] = 0xFFFFFFFFu;

    const unsigned char* myb0 = sE + t * 32768 + nrow;           // even pair
    const unsigned char* myb1 = sE + 65536 + t * 32768 + nrow;   // odd pair
    const unsigned nbase = (unsigned)(t * 64 + wn * 32 + c);

    for (int ct = 0; ct < 32; ct++) {
        // pair ct resident: the 16 newest in-flight ops are pair ct+1's
        if (ct == 31) asm volatile("s_waitcnt vmcnt(0)" ::: "memory");
        else          asm volatile("s_waitcnt vmcnt(16)" ::: "memory");
        __builtin_amdgcn_s_barrier();

        const unsigned char* sB = (ct & 1) ? myb1 : myb0;
        float en = sEn[ct * 128 + nbase];
        float pre = fmaf(en, KSCL, KOFF);
        v16f a0 = (v16f)(0.0f), a1 = (v16f)(0.0f);
        v16f b0 = (v16f)(0.0f), b1 = (v16f)(0.0f);
#pragma unroll
        for (int kt = 0; kt < 8; kt++) {
            int G = kt * 4 + 2 * h;
            union { uint4 u[2]; v8i v; } bv;
            bv.u[0] = *(const uint4*)(sB + (((G    ) ^ c) * 16));
            bv.u[1] = *(const uint4*)(sB + (((G + 1) ^ c) * 16));
            if (kt & 1) {
                a1 = __builtin_amdgcn_mfma_scale_f32_32x32x64_f8f6f4(
                    za[0][kt], bv.v, a1, 0, 0, 0, 0x7F, 0, 0x7F);
                b1 = __builtin_amdgcn_mfma_scale_f32_32x32x64_f8f6f4(
                    za[1][kt], bv.v, b1, 0, 0, 0, 0x7F, 0, 0x7F);
            } else {
                a0 = __builtin_amdgcn_mfma_scale_f32_32x32x64_f8f6f4(
                    za[0][kt], bv.v, a0, 0, 0, 0, 0x7F, 0, 0x7F);
                b0 = __builtin_amdgcn_mfma_scale_f32_32x32x64_f8f6f4(
                    za[1][kt], bv.v, b0, 0, 0, 0, 0x7F, 0, 0x7F);
            }
        }

        asm volatile("s_waitcnt lgkmcnt(0)" ::: "memory"); // ds reads of buf done
        __builtin_amdgcn_s_barrier();     // all waves done reading pair buf

        if (ct < 30) {                    // stage pair ct+2 into buf[ct&1]
            unsigned char* sD = sE + (ct & 1) * 65536;
            const unsigned char* ebase = e8 + (size_t)(ct + 2) * 65536;
#pragma unroll
            for (int s = 0; s < 16; s++)
                gld16(ebase + eoff[s], sD + (wv * 16 + s) * 1024);
        }

        // deferred score: overlaps with next pair's DMA flight time
        unsigned n = nbase + (unsigned)ct * 128u;
#pragma unroll
        for (int reg = 0; reg < 16; reg++) {
            float s0 = a0[reg] + a1[reg];
            unsigned k0 = (unsigned)fmaf(s0, -64.0f, pre);   // trunc; monotone
            unsigned p0 = (k0 << 12) | n;
            runmin[0][reg] = runmin[0][reg] < p0 ? runmin[0][reg] : p0;
            float s1 = b0[reg] + b1[reg];
            unsigned k1 = (unsigned)fmaf(s1, -64.0f, pre);
            unsigned p1 = (k1 << 12) | n;
            runmin[1][reg] = runmin[1][reg] < p1 ? runmin[1][reg] : p1;
        }
    }

    // ---- cross-lane reduce (32 cols), then cross-wave combine via LDS
    __syncthreads();                      // done with buffers -> reuse as scratch
    unsigned* tmp = (unsigned*)sE;        // [4 waves][64 rows]
#pragma unroll
    for (int m = 0; m < 2; m++) {
#pragma unroll
        for (int reg = 0; reg < 16; reg++) {
            unsigned v = runmin[m][reg];
#pragma unroll
            for (int off = 1; off < 32; off <<= 1) {
                unsigned o = (unsigned)__shfl_xor((int)v, off);
                v = v < o ? v : o;
            }
            if (c == 0) {
                int r = m * 32 + (reg & 3) + 8 * (reg >> 2) + 4 * h;
                tmp[wv * 64 + r] = v;
            }
        }
    }
    __syncthreads();
    if (tid < 64) {                       // combine the 4 waves' disjoint code sets
        unsigned v0 = tmp[tid], v1 = tmp[64 + tid];
        unsigned v2 = tmp[128 + tid], v3 = tmp[192 + tid];
        unsigned a = v0 < v1 ? v0 : v1, b = v2 < v3 ? v2 : v3;
        rowmin[row0 + tid] = a < b ? a : b;
    }
}

// ---------------- 4. gather + STE output + sse + hist -------------
__global__ void gather_loss(const float* __restrict__ z, const float* __restrict__ emb,
                            const unsigned* __restrict__ rowmin,
                            float* __restrict__ out, double* __restrict__ sse,
                            unsigned* __restrict__ counts) {
    int i = blockIdx.x * blockDim.x + threadIdx.x;   // f4 index, 4194304 total
    float4 zv = ((const float4*)z)[i];
    int row = i >> 7, col = i & 127;
    unsigned code = rowmin[row] & 0xFFFu;
    if (col == 0) atomicAdd(&counts[code], 1u);      // fused histogram: one lane per row
    float4 q = ((const float4*)emb)[code * 128 + col];
    float4 dv = make_float4(q.x - zv.x, q.y - zv.y, q.z - zv.z, q.w - zv.w);
    float4 o  = make_float4(zv.x + dv.x, zv.y + dv.y, zv.z + dv.z, zv.w + dv.w);
    ((float4*)out)[i] = o;
    double loc = (double)dv.x*dv.x + (double)dv.y*dv.y + (double)dv.z*dv.z + (double)dv.w*dv.w;
    for (int off = 32; off; off >>= 1) loc += __shfl_down(loc, off);
    __shared__ double sw[4];
    if ((threadIdx.x & 63) == 0) sw[threadIdx.x >> 6] = loc;
    __syncthreads();
    if (threadIdx.x == 0)
        atomicAdd(&sse[blockIdx.x & 255], sw[0] + sw[1] + sw[2] + sw[3]);  // 256 slots
}

// ---------------- 5. losses + perplexity -------------
__global__ void finalize(const unsigned* __restrict__ counts, const double* __restrict__ sse,
                         float* __restrict__ out) {
    __shared__ double sh[256], sv[256];
    double h = 0.0;
    for (int b = threadIdx.x; b < NCODE; b += 256) {
        double p = (double)counts[b] / (double)NTOK;
        h += p * log(p + 1e-10);
    }
    sh[threadIdx.x] = h;
    sv[threadIdx.x] = sse[threadIdx.x];
    __syncthreads();
    for (int off = 128; off > 0; off >>= 1) {
        if (threadIdx.x < off) {
            sh[threadIdx.x] += sh[threadIdx.x + off];
            sv[threadIdx.x] += sv[threadIdx.x + off];
        }
        __syncthreads();
    }
    if (threadIdx.x == 0) {
        out[NELEM]     = (float)((1.0 + COMMIT) * sv[0] / (double)NELEM);  // vq_loss
        out[NELEM + 1] = (float)exp(-sh[0]);                                // perplexity
    }
}

// ---------------- launch ----------------
extern "C" void kernel_launch(void* const* d_in, const int* in_sizes, int n_in,
                              void* d_out, int out_size, void* d_ws, size_t ws_size,
                              hipStream_t stream) {
    const float* z   = (const float*)d_in[0];
    const float* emb = (const float*)d_in[1];
    float* out = (float*)d_out;
    char* ws = (char*)d_ws;

    unsigned* z8 = (unsigned*)(ws + OFF_Z8);
    unsigned* e8 = (unsigned*)(ws + OFF_E8);
    float*    en32 = (float*)(ws + OFF_EN32);
    unsigned* rowmin = (unsigned*)(ws + OFF_ROWMIN);
    unsigned* counts = (unsigned*)(ws + OFF_COUNTS);
    double*   sse    = (double*)(ws + OFF_SSE);

    conv_kernel<<<(NELEM/16 + (NCODE*DIM)/16 + 255) / 256, 256, 0, stream>>>(
        z, emb, z8, e8, counts, sse);
    enorm_kernel<<<(NCODE * 64) / 256, 256, 0, stream>>>(emb, en32);

    score_pass<<<NTOK / 64, 256, 0, stream>>>((const unsigned char*)z8,
                                              (const unsigned char*)e8, en32, rowmin);

    gather_loss<<<NELEM / 4 / 256, 256, 0, stream>>>(z, emb, rowmin, out, sse, counts);
    finalize<<<1, 256, 0, stream>>>(counts, sse, out);
}